// Round 14
// baseline (267.875 us; speedup 1.0000x reference)
//
#include <hip/hip_runtime.h>

// B=8, T=1024, D=1024, H=16, Dh=64. x/w/b fp32 (probe-verified; dual path
// kept), lengths int32, output dtype follows probe flag.
//
// R20 = R19 (264.4us best) + launch-count reduction. Budget ledger: kernels
// sum to ~202-210us (gemm_qkv 82.7 + attn 74-81 + gemm_out ~27 + cvt 8 +
// transp 4 + probe 2) vs 264.4 total -> ~55-60us of inter-launch overhead
// across 7 serial launches (~10us each, matches rocprof.md). Changes:
//   - self-probe (2KB wave-local scan of x, L2-broadcast) replaces the flag
//     kernel+buffer entirely.
//   - prep_k fuses cvt_x + both weight transposes (block-role by blockIdx).
//   - launches 7 -> 4: prep, gemm_qkv, attn, gemm_out.
// gemm/attn compute structures are R19-identical.

typedef __attribute__((ext_vector_type(8))) short bf16x8;
typedef __attribute__((ext_vector_type(4))) float f32x4;

__device__ inline short f2b(float f) {
  unsigned u = __float_as_uint(f);
  unsigned r = (u + 0x7fff + ((u >> 16) & 1)) >> 16;
  return (short)r;
}
__device__ inline float b2f(short s) {
  return __uint_as_float(((unsigned)(unsigned short)s) << 16);
}

__device__ inline bf16x8 ld8(const char* p, int isf32) {
  if (isf32) {
    const float* f = (const float*)p;
    bf16x8 r;
#pragma unroll
    for (int j = 0; j < 8; j++) r[j] = f2b(f[j]);
    return r;
  }
  return *(const bf16x8*)p;
}

__device__ inline float ldbias(const char* b, int n, int isf32) {
  return isf32 ? ((const float*)b)[n] : b2f(((const short*)b)[n]);
}

__device__ inline void gl_lds16(const short* g, short* l) {
  __builtin_amdgcn_global_load_lds(
      (const __attribute__((address_space(1))) void*)g,
      (__attribute__((address_space(3))) void*)l, 16, 0, 0);
}

// Wave-local dtype probe: scan first 1024 elements' exponent field of x
// (2KB, L2-broadcast after first touch). Verbatim logic from the original
// probe_k (f32 mantissa shorts trip e>=0x90 ~44% of the time; bf16 normals
// never). Every wave computes the same block-uniform answer.
__device__ inline int self_probe(const short* xs) {
  int lane = threadIdx.x & 63;
  int cnt = 0;
  for (int i = lane; i < 1024; i += 64) {
    int e = (xs[2 * i] >> 7) & 0xFF;
    cnt += (e >= 0x90) ? 1 : 0;
  }
#pragma unroll
  for (int o = 1; o < 64; o <<= 1) cnt += __shfl_xor(cnt, o);
  return cnt > 100 ? 1 : 0;
}

// ---------------- prep: cvt_x + both weight transposes, fused -------------
// Grid: [0, nb*512)            -> cvt blocks (x -> xbf for this pass)
//       [nb*512, +768)         -> w_qkv transpose tiles (48 x 16), b0==0 only
//       [nb*512+768, +256)     -> w_o transpose tiles (16 x 16),  b0==0 only
__global__ __launch_bounds__(256) void prep_k(
    const char* __restrict__ x, short* __restrict__ xb,
    const char* __restrict__ w_qkv, short* __restrict__ wT_qkv,
    const char* __restrict__ w_o, short* __restrict__ wT_o, int b_base,
    int nb) {
  __shared__ __align__(16) short tile[64][80];
  int isf32 = self_probe((const short*)x);
  size_t esz = isf32 ? 4 : 2;
  int bid = blockIdx.x;
  int ncvt = nb * 512;
  int t = threadIdx.x;
  if (bid < ncvt) {
    size_t i = ((size_t)bid * 256 + t) * 8;
    size_t g = (size_t)b_base * 1024 * 1024 + i;
    *(bf16x8*)(xb + i) = ld8(x + g * esz, isf32);
    return;
  }
  if (b_base > 0) return;  // weights already transposed in first pass
  bid -= ncvt;
  const char* in;
  short* outp;
  int C, bx, by;
  if (bid < 768) {
    in = w_qkv; outp = wT_qkv; C = 3072;
    bx = bid % 48; by = bid / 48;
  } else {
    bid -= 768;
    in = w_o; outp = wT_o; C = 1024;
    bx = bid & 15; by = bid >> 4;
  }
  const int R = 1024;
  int r0 = by * 64, c0 = bx * 64;
#pragma unroll
  for (int i = 0; i < 2; i++) {
    int s = i * 256 + t;
    int rr = s >> 3, cc = (s & 7) * 8;
    *(bf16x8*)&tile[rr][cc] =
        ld8(in + ((size_t)(r0 + rr) * C + c0 + cc) * esz, isf32);
  }
  __syncthreads();
#pragma unroll
  for (int i = 0; i < 2; i++) {
    int s = i * 256 + t;
    int cc2 = s >> 3, rr2 = (s & 7) * 8;
    bf16x8 v;
#pragma unroll
    for (int j = 0; j < 8; j++) v[j] = tile[rr2 + j][cc2];
    *(bf16x8*)(outp + (size_t)(c0 + cc2) * R + r0 + rr2) = v;
  }
}

// ---------------- GEMM core (R14): 128x128, K=1024 --------------------------
// 3 buffers x BK=32, prefetch distance 2, counted vmcnt(8/4/0), raw barriers.
template <int CUR, int MODE>
__device__ __forceinline__ void gstep(const short* __restrict__ Ab,
                                      const short* __restrict__ Bb, short* Ls,
                                      int ktn, int t, int srow, int lk, int wm,
                                      int wn, int col, int quad,
                                      f32x4 (&acc)[4][4]) {
  if (MODE == 0) {
    constexpr int SB = (CUR + 2) % 3;
    short* Ad = Ls + SB * 8192;
    short* Bd = Ad + 4096;
    gl_lds16(Ab + (size_t)srow * 1024 + ktn + lk, Ad + t * 8);
    gl_lds16(Ab + (size_t)(srow + 64) * 1024 + ktn + lk, Ad + 2048 + t * 8);
    gl_lds16(Bb + (size_t)srow * 1024 + ktn + lk, Bd + t * 8);
    gl_lds16(Bb + (size_t)(srow + 64) * 1024 + ktn + lk, Bd + 2048 + t * 8);
    asm volatile("s_waitcnt vmcnt(8)" ::: "memory");
  } else if (MODE == 1) {
    asm volatile("s_waitcnt vmcnt(4)" ::: "memory");
  } else {
    asm volatile("s_waitcnt vmcnt(0)" ::: "memory");
  }
  __builtin_amdgcn_sched_barrier(0);
  __builtin_amdgcn_s_barrier();

  const short* Ac = Ls + CUR * 8192;
  const short* Bc = Ac + 4096;
  bf16x8 af[4], bfr[4];
#pragma unroll
  for (int i = 0; i < 4; i++)
    af[i] = *(const bf16x8*)(Ac + (wm + i * 16 + col) * 32 + quad * 8);
#pragma unroll
  for (int i = 0; i < 4; i++)
    bfr[i] = *(const bf16x8*)(Bc + (wn + i * 16 + col) * 32 + quad * 8);
  __builtin_amdgcn_s_setprio(1);
#pragma unroll
  for (int i = 0; i < 4; i++)
#pragma unroll
    for (int j = 0; j < 4; j++)
      acc[i][j] = __builtin_amdgcn_mfma_f32_16x16x32_bf16(af[i], bfr[j],
                                                          acc[i][j], 0, 0, 0);
  __builtin_amdgcn_s_setprio(0);
  __builtin_amdgcn_s_barrier();
}

__device__ inline void gemm_core(const short* __restrict__ A,
                                 const short* __restrict__ Bt, short* Ls,
                                 int m0, int n0, f32x4 (&acc)[4][4]) {
  int t = threadIdx.x;
  int lane = t & 63, wave = t >> 6, quad = lane >> 4, col = lane & 15;
  int wm = (wave >> 1) * 64, wn = (wave & 1) * 64;
  const short* Ab = A + (size_t)m0 * 1024;
  const short* Bb = Bt + (size_t)n0 * 1024;
  int srow = t >> 2, lk = (t & 3) * 8;

  gl_lds16(Ab + (size_t)srow * 1024 + lk, Ls + t * 8);
  gl_lds16(Ab + (size_t)(srow + 64) * 1024 + lk, Ls + 2048 + t * 8);
  gl_lds16(Bb + (size_t)srow * 1024 + lk, Ls + 4096 + t * 8);
  gl_lds16(Bb + (size_t)(srow + 64) * 1024 + lk, Ls + 4096 + 2048 + t * 8);
  gl_lds16(Ab + (size_t)srow * 1024 + 32 + lk, Ls + 8192 + t * 8);
  gl_lds16(Ab + (size_t)(srow + 64) * 1024 + 32 + lk, Ls + 8192 + 2048 + t * 8);
  gl_lds16(Bb + (size_t)srow * 1024 + 32 + lk, Ls + 8192 + 4096 + t * 8);
  gl_lds16(Bb + (size_t)(srow + 64) * 1024 + 32 + lk,
           Ls + 8192 + 4096 + 2048 + t * 8);

  for (int g = 0; g < 10; g++) {
    int kb = g * 96;
    gstep<0, 0>(Ab, Bb, Ls, kb + 64, t, srow, lk, wm, wn, col, quad, acc);
    gstep<1, 0>(Ab, Bb, Ls, kb + 96, t, srow, lk, wm, wn, col, quad, acc);
    gstep<2, 0>(Ab, Bb, Ls, kb + 128, t, srow, lk, wm, wn, col, quad, acc);
  }
  gstep<0, 1>(Ab, Bb, Ls, 0, t, srow, lk, wm, wn, col, quad, acc);
  gstep<1, 2>(Ab, Bb, Ls, 0, t, srow, lk, wm, wn, col, quad, acc);
}

// GEMM1. Grid (24, nb*8). Q pre-scaled by 0.125 (exact).
// R19 skip: blocks fully masked (mloc >= len) return before any barrier;
// attn provably never reads those Qb/Kb/VTb regions.
__global__ __launch_bounds__(256, 3) void gemm_qkv_k(
    const short* __restrict__ xbf, const short* __restrict__ wT,
    const char* __restrict__ bias, short* __restrict__ Qb,
    short* __restrict__ Kb, short* __restrict__ VTb,
    const char* __restrict__ x, const int* __restrict__ lengths, int b_base) {
  __shared__ __align__(16) short Ls[3 * 8192];
  int m0 = blockIdx.y * 128, n0 = blockIdx.x * 128;
  int bll = m0 >> 10;
  int len = lengths[b_base + bll];
  int mloc = m0 & 1023;
  if (mloc >= len) return;  // block-uniform, before any barrier

  int isf32 = self_probe((const short*)x);
  f32x4 acc[4][4];
#pragma unroll
  for (int i = 0; i < 4; i++)
#pragma unroll
    for (int j = 0; j < 4; j++) acc[i][j] = f32x4{0.f, 0.f, 0.f, 0.f};
  gemm_core(xbf, wT, Ls, m0, n0, acc);
  int t = threadIdx.x, wave = t >> 6, lane = t & 63, quad = lane >> 4,
      col = lane & 15;
  int wm = (wave >> 1) * 64, wn = (wave & 1) * 64;
#pragma unroll
  for (int j = 0; j < 4; j++) {
    int n = n0 + wn + j * 16 + col;
    float bv = ldbias(bias, n, isf32);
    int qi = n >> 10, d = n & 1023, h = d >> 6, dh = d & 63;
#pragma unroll
    for (int i = 0; i < 4; i++) {
#pragma unroll
      for (int r = 0; r < 4; r++) {
        int m = m0 + wm + i * 16 + quad * 4 + r;
        int bl = m >> 10, tp = m & 1023;
        size_t bh = (size_t)bl * 16 + h;
        float val = acc[i][j][r] + bv;
        if (qi == 0)
          Qb[(bh * 1024 + tp) * 64 + dh] = f2b(val * 0.125f);
        else if (qi == 1)
          Kb[(bh * 1024 + tp) * 64 + dh] = f2b(val);
        else
          VTb[(bh * 64 + dh) * 1024 + tp] = f2b(val);
      }
    }
  }
}

// attention. Grid (8, nb*16), 4 waves; each wave owns 32 q-rows (2 q-tiles).
// R18 structure: K LDS-staged distance-1 dbuf, one __syncthreads per tile,
// V via T14 register prefetch, wave-private P round-trip, early-exit.
__global__ __launch_bounds__(256, 4) void attn_k(
    const short* __restrict__ Qb, const short* __restrict__ Kb,
    const short* __restrict__ VTb, const int* __restrict__ lengths,
    short* __restrict__ Ob, int b_base) {
  __shared__ __align__(16) short Ks[2][2][64 * 32];  // [buf][half][key][d]
  __shared__ __align__(16) short Pl[4 * 32 * 72];
  int t = threadIdx.x, wave = t >> 6, lane = t & 63, quad = lane >> 4,
      col = lane & 15;
  int bh = blockIdx.y, bl = bh >> 4, h = bh & 15;
  int len = lengths[b_base + bl];
  int qblk = blockIdx.x * 128;
  if (qblk >= len) {
    bf16x8 z;
#pragma unroll
    for (int j = 0; j < 8; j++) z[j] = 0;
    int rr = t >> 1, cc = (t & 1) * 32;
    short* dst = Ob + ((size_t)bl * 1024 + qblk + rr) * 1024 + h * 64 + cc;
#pragma unroll
    for (int j = 0; j < 4; j++) *(bf16x8*)(dst + j * 8) = z;
    return;
  }
  int qb0 = qblk + wave * 16;  // qt adds +64
  const short* Q = Qb + (size_t)bh * 1024 * 64;
  const short* K = Kb + (size_t)bh * 1024 * 64;
  const short* VT = VTb + (size_t)bh * 64 * 1024;
  short* myP = Pl + wave * 32 * 72;

  int srow = t >> 2, skk = (t & 3) * 8;

  bf16x8 qf[2][2];
#pragma unroll
  for (int qt = 0; qt < 2; qt++) {
    qf[qt][0] = *(const bf16x8*)(Q + (qb0 + qt * 64 + col) * 64 + quad * 8);
    qf[qt][1] =
        *(const bf16x8*)(Q + (qb0 + qt * 64 + col) * 64 + 32 + quad * 8);
  }

  f32x4 oacc[2][4];
  float suml[2][4];
#pragma unroll
  for (int qt = 0; qt < 2; qt++)
#pragma unroll
    for (int i = 0; i < 4; i++) {
      oacc[qt][i] = f32x4{0.f, 0.f, 0.f, 0.f};
      suml[qt][i] = 0.f;
    }

  int klim = ((len + 63) >> 6) << 6;  // block-uniform, <= 1024

  gl_lds16(K + (size_t)srow * 64 + skk, Ks[0][0] + t * 8);
  gl_lds16(K + (size_t)srow * 64 + 32 + skk, Ks[0][1] + t * 8);
  __syncthreads();

  for (int k0 = 0; k0 < klim; k0 += 64) {
    int cur = (k0 >> 6) & 1;
    if (k0 + 64 < klim) {
      int nx = cur ^ 1, kn = k0 + 64;
      gl_lds16(K + (size_t)(kn + srow) * 64 + skk, Ks[nx][0] + t * 8);
      gl_lds16(K + (size_t)(kn + srow) * 64 + 32 + skk, Ks[nx][1] + t * 8);
    }

    // T14: issue V loads for nt=0,1 now; consumed after QK (~600cy cover).
    bf16x8 vr[4][2];
#pragma unroll
    for (int nt = 0; nt < 2; nt++) {
      vr[nt][0] = *(const bf16x8*)(VT + (size_t)(nt * 16 + col) * 1024 + k0 +
                                   quad * 8);
      vr[nt][1] = *(const bf16x8*)(VT + (size_t)(nt * 16 + col) * 1024 + k0 +
                                   32 + quad * 8);
    }

#pragma unroll
    for (int qt = 0; qt < 2; qt++) {
      f32x4 s[4];
#pragma unroll
      for (int ks = 0; ks < 4; ks++) s[ks] = f32x4{0.f, 0.f, 0.f, 0.f};
      __builtin_amdgcn_s_setprio(1);
#pragma unroll
      for (int ks = 0; ks < 4; ks++) {
        bf16x8 klo =
            *(const bf16x8*)(Ks[cur][0] + (ks * 16 + col) * 32 + quad * 8);
        bf16x8 khi =
            *(const bf16x8*)(Ks[cur][1] + (ks * 16 + col) * 32 + quad * 8);
        s[ks] = __builtin_amdgcn_mfma_f32_16x16x32_bf16(qf[qt][0], klo, s[ks],
                                                        0, 0, 0);
        s[ks] = __builtin_amdgcn_mfma_f32_16x16x32_bf16(qf[qt][1], khi, s[ks],
                                                        0, 0, 0);
      }
      __builtin_amdgcn_s_setprio(0);
#pragma unroll
      for (int ks = 0; ks < 4; ks++) {
#pragma unroll
        for (int r = 0; r < 4; r++) {
          float e = (k0 + ks * 16 + col < len) ? __expf(s[ks][r]) : 0.f;
          suml[qt][r] += e;
          myP[(qt * 16 + quad * 4 + r) * 72 + ks * 16 + col] = f2b(e);
        }
      }
    }

    // T14: issue V loads for nt=2,3; consumed after the P round-trip.
#pragma unroll
    for (int nt = 2; nt < 4; nt++) {
      vr[nt][0] = *(const bf16x8*)(VT + (size_t)(nt * 16 + col) * 1024 + k0 +
                                   quad * 8);
      vr[nt][1] = *(const bf16x8*)(VT + (size_t)(nt * 16 + col) * 1024 + k0 +
                                   32 + quad * 8);
    }

#pragma unroll
    for (int qt = 0; qt < 2; qt++) {
      bf16x8 pf0 = *(const bf16x8*)(myP + (qt * 16 + col) * 72 + quad * 8);
      bf16x8 pf1 = *(const bf16x8*)(myP + (qt * 16 + col) * 72 + 32 + quad * 8);
      __builtin_amdgcn_s_setprio(1);
#pragma unroll
      for (int nt = 0; nt < 4; nt++) {
        oacc[qt][nt] = __builtin_amdgcn_mfma_f32_16x16x32_bf16(
            pf0, vr[nt][0], oacc[qt][nt], 0, 0, 0);
        oacc[qt][nt] = __builtin_amdgcn_mfma_f32_16x16x32_bf16(
            pf1, vr[nt][1], oacc[qt][nt], 0, 0, 0);
      }
      __builtin_amdgcn_s_setprio(0);
    }
    __syncthreads();
  }
#pragma unroll
  for (int qt = 0; qt < 2; qt++)
#pragma unroll
    for (int r = 0; r < 4; r++) {
      suml[qt][r] += __shfl_xor(suml[qt][r], 1);
      suml[qt][r] += __shfl_xor(suml[qt][r], 2);
      suml[qt][r] += __shfl_xor(suml[qt][r], 4);
      suml[qt][r] += __shfl_xor(suml[qt][r], 8);
    }
#pragma unroll
  for (int qt = 0; qt < 2; qt++)
#pragma unroll
    for (int nt = 0; nt < 4; nt++)
#pragma unroll
      for (int r = 0; r < 4; r++) {
        int q = qb0 + qt * 64 + quad * 4 + r;
        float v = (q < len) ? oacc[qt][nt][r] / suml[qt][r] : 0.f;
        Ob[((size_t)bl * 1024 + q) * 1024 + h * 64 + nt * 16 + col] = f2b(v);
      }
}

// GEMM2. Grid (8, nb*8). Output dtype follows probe.
// R19 skip: fully-masked blocks write the bias broadcast (0 @ w_o + b_o).
__global__ __launch_bounds__(256, 3) void gemm_out_k(
    const short* __restrict__ O, const short* __restrict__ wT,
    const char* __restrict__ bias, char* __restrict__ out,
    const char* __restrict__ x, int m_base, const int* __restrict__ lengths) {
  __shared__ __align__(16) short Ls[3 * 8192];
  int isf32 = self_probe((const short*)x);
  int m0 = blockIdx.y * 128, n0 = blockIdx.x * 128;
  int gm = m_base + m0;
  int len = lengths[gm >> 10];
  int mloc = gm & 1023;
  if (mloc >= len) {
    int t = threadIdx.x;
    int nn = n0 + (t & 127);
    float bv = ldbias(bias, nn, isf32);
    int mstart = m0 + (t >> 7) * 64;
    for (int j = 0; j < 64; j++) {
      size_t idx = (size_t)(m_base + mstart + j) * 1024 + nn;
      if (isf32)
        ((float*)out)[idx] = bv;
      else
        ((short*)out)[idx] = f2b(bv);
    }
    return;
  }
  f32x4 acc[4][4];
#pragma unroll
  for (int i = 0; i < 4; i++)
#pragma unroll
    for (int j = 0; j < 4; j++) acc[i][j] = f32x4{0.f, 0.f, 0.f, 0.f};
  gemm_core(O, wT, Ls, m0, n0, acc);
  int t = threadIdx.x, wave = t >> 6, lane = t & 63, quad = lane >> 4,
      col = lane & 15;
  int wm = (wave >> 1) * 64, wn = (wave & 1) * 64;
#pragma unroll
  for (int j = 0; j < 4; j++) {
    int n = n0 + wn + j * 16 + col;
    float bv = ldbias(bias, n, isf32);
#pragma unroll
    for (int i = 0; i < 4; i++) {
#pragma unroll
      for (int r = 0; r < 4; r++) {
        int m = m0 + wm + i * 16 + quad * 4 + r;
        size_t idx = (size_t)(m_base + m) * 1024 + n;
        float val = acc[i][j][r] + bv;
        if (isf32)
          ((float*)out)[idx] = val;
        else
          ((short*)out)[idx] = f2b(val);
      }
    }
  }
}

extern "C" void kernel_launch(void* const* d_in, const int* in_sizes, int n_in,
                              void* d_out, int out_size, void* d_ws,
                              size_t ws_size, hipStream_t stream) {
  const char* x = (const char*)d_in[0];
  const int* lengths = (const int*)d_in[1];
  const char* w_qkv = (const char*)d_in[2];
  const char* b_qkv = (const char*)d_in[3];
  const char* w_o = (const char*)d_in[4];
  const char* b_o = (const char*)d_in[5];
  char* out = (char*)d_out;

  char* ws = (char*)d_ws;
  ws += 256;  // (former flag slot; layout kept)
  short* wT_qkv = (short*)ws;  ws += (size_t)3072 * 1024 * 2;  // 6.3 MB
  short* wT_o = (short*)ws;    ws += (size_t)1024 * 1024 * 2;  // 2.1 MB
  char* dynbase = ws;
  size_t fixed = (size_t)(dynbase - (char*)d_ws);
  size_t per_batch = (size_t)16 * 1024 * 64 * 2;  // 2.10 MB / tensor
  size_t need_full = fixed + 4 * 8 * per_batch;   // ~75.8 MB (fits, R3-R5)
  int nb = (ws_size >= need_full) ? 8 : 1;

  // xbf aliases Ob: x consumed by GEMM1 before attn writes Ob.
  short* xbf_Ob = (short*)dynbase;
  short* Qb = xbf_Ob + (size_t)nb * 16 * 1024 * 64;
  short* Kb = Qb + (size_t)nb * 16 * 1024 * 64;
  short* VTb = Kb + (size_t)nb * 16 * 1024 * 64;

  dim3 blk(256);
  for (int b0 = 0; b0 < 8; b0 += nb) {
    prep_k<<<dim3(nb * 512 + 1024), blk, 0, stream>>>(x, xbf_Ob, w_qkv,
                                                      wT_qkv, w_o, wT_o, b0,
                                                      nb);
    gemm_qkv_k<<<dim3(24, nb * 8), blk, 0, stream>>>(xbf_Ob, wT_qkv, b_qkv, Qb,
                                                     Kb, VTb, x, lengths, b0);
    attn_k<<<dim3(8, nb * 16), blk, 0, stream>>>(Qb, Kb, VTb, lengths, xbf_Ob,
                                                 b0);
    gemm_out_k<<<dim3(8, nb * 8), blk, 0, stream>>>(xbf_Ob, wT_o, b_o, out, x,
                                                    b0 * 1024, lengths);
  }
}

// Round 15
// 261.482 us; speedup vs baseline: 1.0245x; 1.0245x over previous
//
#include <hip/hip_runtime.h>

// B=8, T=1024, D=1024, H=16, Dh=64. x/w/b fp32 (probe-verified; dual path
// kept), lengths int32, output dtype follows probe flag.
//
// R21 = R19 (264.4 best; R20's launch-fusion regressed -3.5 -> reverted) +
// correct per-phase bank fix. Analysis: fragment reads (row*32+quad*8, 64B
// row stride) are a 4-WAY conflict per 8-lane phase (cols{0,2,4,6}->banks
// 0-3, odds->16-19) in gemm_core AND attn K -- the constant 6.29/4.82M
// counter. LDS-read pipe ~96KB/CU/iter = 750cy free / 1185cy at 1.58x >
// 230cy MFMA slice -> plausible cause of five null schedule variants.
// Fix (R16-proven both-sides): stage global chunk (t&3)^((srow>>1)&3) at
// linear slot t&3; read slot quad^((col>>1)&3). Banks per 8-lane phase =
// 16*(col&1)+4*slot = all 32 distinct -> conflict-free.

typedef __attribute__((ext_vector_type(8))) short bf16x8;
typedef __attribute__((ext_vector_type(4))) float f32x4;

__device__ inline short f2b(float f) {
  unsigned u = __float_as_uint(f);
  unsigned r = (u + 0x7fff + ((u >> 16) & 1)) >> 16;
  return (short)r;
}
__device__ inline float b2f(short s) {
  return __uint_as_float(((unsigned)(unsigned short)s) << 16);
}

__device__ inline bf16x8 ld8(const char* p, int isf32) {
  if (isf32) {
    const float* f = (const float*)p;
    bf16x8 r;
#pragma unroll
    for (int j = 0; j < 8; j++) r[j] = f2b(f[j]);
    return r;
  }
  return *(const bf16x8*)p;
}

__device__ inline float ldbias(const char* b, int n, int isf32) {
  return isf32 ? ((const float*)b)[n] : b2f(((const short*)b)[n]);
}

__device__ inline void gl_lds16(const short* g, short* l) {
  __builtin_amdgcn_global_load_lds(
      (const __attribute__((address_space(1))) void*)g,
      (__attribute__((address_space(3))) void*)l, 16, 0, 0);
}

// ---------------- dtype probe (1 block x 64) --------------------------------
__global__ void probe_k(const short* __restrict__ xs, int* __restrict__ flag) {
  int lane = threadIdx.x & 63;
  int cnt = 0;
  for (int i = lane; i < 1024; i += 64) {
    int e = (xs[2 * i] >> 7) & 0xFF;
    cnt += (e >= 0x90) ? 1 : 0;
  }
#pragma unroll
  for (int o = 1; o < 64; o <<= 1) cnt += __shfl_xor(cnt, o);
  if (lane == 0) *flag = (cnt > 100) ? 1 : 0;
}

// ---------------- x -> bf16 -------------------------------------------------
__global__ __launch_bounds__(256) void cvt_x_k(const char* __restrict__ x,
                                               short* __restrict__ xb,
                                               const int* __restrict__ flag,
                                               int b_base) {
  int isf32 = *flag;
  size_t esz = isf32 ? 4 : 2;
  size_t i = ((size_t)blockIdx.x * 256 + threadIdx.x) * 8;
  size_t g = (size_t)b_base * 1024 * 1024 + i;
  *(bf16x8*)(xb + i) = ld8(x + g * esz, isf32);
}

// ---------------- transpose out[c][r] = in[r][c] ----------------------------
__global__ __launch_bounds__(256) void transpose_k(
    const char* __restrict__ in, short* __restrict__ out, int R, int C,
    const int* __restrict__ flag) {
  __shared__ __align__(16) short tile[64][80];
  int isf32 = *flag;
  size_t esz = isf32 ? 4 : 2;
  int t = threadIdx.x;
  int r0 = blockIdx.y * 64, c0 = blockIdx.x * 64;
#pragma unroll
  for (int i = 0; i < 2; i++) {
    int s = i * 256 + t;
    int rr = s >> 3, cc = (s & 7) * 8;
    *(bf16x8*)&tile[rr][cc] =
        ld8(in + ((size_t)(r0 + rr) * C + c0 + cc) * esz, isf32);
  }
  __syncthreads();
#pragma unroll
  for (int i = 0; i < 2; i++) {
    int s = i * 256 + t;
    int cc2 = s >> 3, rr2 = (s & 7) * 8;
    bf16x8 v;
#pragma unroll
    for (int j = 0; j < 8; j++) v[j] = tile[rr2 + j][cc2];
    *(bf16x8*)(out + (size_t)(c0 + cc2) * R + r0 + rr2) = v;
  }
}

// ---------------- GEMM core (R14 + R21 swizzle): 128x128, K=1024 ------------
// 3 buffers x BK=32, prefetch distance 2, counted vmcnt(8/4/0), raw barriers.
// LDS[row][slot] holds global chunk slot ^ ((row>>1)&3); read slot =
// quad ^ ((col>>1)&3) (per-lane constant; fragment-row bases = 0 mod 8).
template <int CUR, int MODE>
__device__ __forceinline__ void gstep(const short* __restrict__ Ab,
                                      const short* __restrict__ Bb, short* Ls,
                                      int ktn, int t, int srow, int lkg,
                                      int wm, int wn, int col, int quad,
                                      int rslot, f32x4 (&acc)[4][4]) {
  if (MODE == 0) {
    constexpr int SB = (CUR + 2) % 3;
    short* Ad = Ls + SB * 8192;
    short* Bd = Ad + 4096;
    gl_lds16(Ab + (size_t)srow * 1024 + ktn + lkg, Ad + t * 8);
    gl_lds16(Ab + (size_t)(srow + 64) * 1024 + ktn + lkg, Ad + 2048 + t * 8);
    gl_lds16(Bb + (size_t)srow * 1024 + ktn + lkg, Bd + t * 8);
    gl_lds16(Bb + (size_t)(srow + 64) * 1024 + ktn + lkg, Bd + 2048 + t * 8);
    asm volatile("s_waitcnt vmcnt(8)" ::: "memory");
  } else if (MODE == 1) {
    asm volatile("s_waitcnt vmcnt(4)" ::: "memory");
  } else {
    asm volatile("s_waitcnt vmcnt(0)" ::: "memory");
  }
  __builtin_amdgcn_sched_barrier(0);
  __builtin_amdgcn_s_barrier();

  const short* Ac = Ls + CUR * 8192;
  const short* Bc = Ac + 4096;
  bf16x8 af[4], bfr[4];
#pragma unroll
  for (int i = 0; i < 4; i++)
    af[i] = *(const bf16x8*)(Ac + (wm + i * 16 + col) * 32 + rslot);
#pragma unroll
  for (int i = 0; i < 4; i++)
    bfr[i] = *(const bf16x8*)(Bc + (wn + i * 16 + col) * 32 + rslot);
  __builtin_amdgcn_s_setprio(1);
#pragma unroll
  for (int i = 0; i < 4; i++)
#pragma unroll
    for (int j = 0; j < 4; j++)
      acc[i][j] = __builtin_amdgcn_mfma_f32_16x16x32_bf16(af[i], bfr[j],
                                                          acc[i][j], 0, 0, 0);
  __builtin_amdgcn_s_setprio(0);
  __builtin_amdgcn_s_barrier();
}

__device__ inline void gemm_core(const short* __restrict__ A,
                                 const short* __restrict__ Bt, short* Ls,
                                 int m0, int n0, f32x4 (&acc)[4][4]) {
  int t = threadIdx.x;
  int lane = t & 63, wave = t >> 6, quad = lane >> 4, col = lane & 15;
  int wm = (wave >> 1) * 64, wn = (wave & 1) * 64;
  const short* Ab = A + (size_t)m0 * 1024;
  const short* Bb = Bt + (size_t)n0 * 1024;
  int srow = t >> 2;
  int lkg = 8 * ((t & 3) ^ ((srow >> 1) & 3));   // swizzled GLOBAL k-chunk
  int rslot = 8 * (quad ^ ((col >> 1) & 3));     // swizzled read slot

  gl_lds16(Ab + (size_t)srow * 1024 + lkg, Ls + t * 8);
  gl_lds16(Ab + (size_t)(srow + 64) * 1024 + lkg, Ls + 2048 + t * 8);
  gl_lds16(Bb + (size_t)srow * 1024 + lkg, Ls + 4096 + t * 8);
  gl_lds16(Bb + (size_t)(srow + 64) * 1024 + lkg, Ls + 4096 + 2048 + t * 8);
  gl_lds16(Ab + (size_t)srow * 1024 + 32 + lkg, Ls + 8192 + t * 8);
  gl_lds16(Ab + (size_t)(srow + 64) * 1024 + 32 + lkg,
           Ls + 8192 + 2048 + t * 8);
  gl_lds16(Bb + (size_t)srow * 1024 + 32 + lkg, Ls + 8192 + 4096 + t * 8);
  gl_lds16(Bb + (size_t)(srow + 64) * 1024 + 32 + lkg,
           Ls + 8192 + 4096 + 2048 + t * 8);

  for (int g = 0; g < 10; g++) {
    int kb = g * 96;
    gstep<0, 0>(Ab, Bb, Ls, kb + 64, t, srow, lkg, wm, wn, col, quad, rslot,
                acc);
    gstep<1, 0>(Ab, Bb, Ls, kb + 96, t, srow, lkg, wm, wn, col, quad, rslot,
                acc);
    gstep<2, 0>(Ab, Bb, Ls, kb + 128, t, srow, lkg, wm, wn, col, quad, rslot,
                acc);
  }
  gstep<0, 1>(Ab, Bb, Ls, 0, t, srow, lkg, wm, wn, col, quad, rslot, acc);
  gstep<1, 2>(Ab, Bb, Ls, 0, t, srow, lkg, wm, wn, col, quad, rslot, acc);
}

// GEMM1. Grid (24, nb*8). Q pre-scaled by 0.125 (exact).
// R19 skip: fully-masked blocks (mloc >= len) return before any barrier.
__global__ __launch_bounds__(256, 3) void gemm_qkv_k(
    const short* __restrict__ xbf, const short* __restrict__ wT,
    const char* __restrict__ bias, short* __restrict__ Qb,
    short* __restrict__ Kb, short* __restrict__ VTb,
    const int* __restrict__ flag, const int* __restrict__ lengths,
    int b_base) {
  __shared__ __align__(16) short Ls[3 * 8192];
  int m0 = blockIdx.y * 128, n0 = blockIdx.x * 128;
  int bll = m0 >> 10;
  int len = lengths[b_base + bll];
  int mloc = m0 & 1023;
  if (mloc >= len) return;

  int isf32 = *flag;
  f32x4 acc[4][4];
#pragma unroll
  for (int i = 0; i < 4; i++)
#pragma unroll
    for (int j = 0; j < 4; j++) acc[i][j] = f32x4{0.f, 0.f, 0.f, 0.f};
  gemm_core(xbf, wT, Ls, m0, n0, acc);
  int t = threadIdx.x, wave = t >> 6, lane = t & 63, quad = lane >> 4,
      col = lane & 15;
  int wm = (wave >> 1) * 64, wn = (wave & 1) * 64;
#pragma unroll
  for (int j = 0; j < 4; j++) {
    int n = n0 + wn + j * 16 + col;
    float bv = ldbias(bias, n, isf32);
    int qi = n >> 10, d = n & 1023, h = d >> 6, dh = d & 63;
#pragma unroll
    for (int i = 0; i < 4; i++) {
#pragma unroll
      for (int r = 0; r < 4; r++) {
        int m = m0 + wm + i * 16 + quad * 4 + r;
        int bl = m >> 10, tp = m & 1023;
        size_t bh = (size_t)bl * 16 + h;
        float val = acc[i][j][r] + bv;
        if (qi == 0)
          Qb[(bh * 1024 + tp) * 64 + dh] = f2b(val * 0.125f);
        else if (qi == 1)
          Kb[(bh * 1024 + tp) * 64 + dh] = f2b(val);
        else
          VTb[(bh * 64 + dh) * 1024 + tp] = f2b(val);
      }
    }
  }
}

// attention. Grid (8, nb*16), 4 waves; each wave owns 32 q-rows (2 q-tiles).
// R18 structure + R21 K-swizzle: Ks[row][slot] holds chunk slot^((row>>1)&3);
// reads use slot quad^((col>>1)&3). V via T14 register prefetch; wave-private
// P round-trip; early-exit zero-fill.
__global__ __launch_bounds__(256, 4) void attn_k(
    const short* __restrict__ Qb, const short* __restrict__ Kb,
    const short* __restrict__ VTb, const int* __restrict__ lengths,
    short* __restrict__ Ob, int b_base) {
  __shared__ __align__(16) short Ks[2][2][64 * 32];  // [buf][half][key][d]
  __shared__ __align__(16) short Pl[4 * 32 * 72];
  int t = threadIdx.x, wave = t >> 6, lane = t & 63, quad = lane >> 4,
      col = lane & 15;
  int bh = blockIdx.y, bl = bh >> 4, h = bh & 15;
  int len = lengths[b_base + bl];
  int qblk = blockIdx.x * 128;
  if (qblk >= len) {
    bf16x8 z;
#pragma unroll
    for (int j = 0; j < 8; j++) z[j] = 0;
    int rr = t >> 1, cc = (t & 1) * 32;
    short* dst = Ob + ((size_t)bl * 1024 + qblk + rr) * 1024 + h * 64 + cc;
#pragma unroll
    for (int j = 0; j < 4; j++) *(bf16x8*)(dst + j * 8) = z;
    return;
  }
  int qb0 = qblk + wave * 16;  // qt adds +64
  const short* Q = Qb + (size_t)bh * 1024 * 64;
  const short* K = Kb + (size_t)bh * 1024 * 64;
  const short* VT = VTb + (size_t)bh * 64 * 1024;
  short* myP = Pl + wave * 32 * 72;

  int srow = t >> 2;
  int skg = 8 * ((t & 3) ^ ((srow >> 1) & 3));  // swizzled global d-chunk
  int rslot = 8 * (quad ^ ((col >> 1) & 3));    // swizzled K read slot

  bf16x8 qf[2][2];
#pragma unroll
  for (int qt = 0; qt < 2; qt++) {
    qf[qt][0] = *(const bf16x8*)(Q + (qb0 + qt * 64 + col) * 64 + quad * 8);
    qf[qt][1] =
        *(const bf16x8*)(Q + (qb0 + qt * 64 + col) * 64 + 32 + quad * 8);
  }

  f32x4 oacc[2][4];
  float suml[2][4];
#pragma unroll
  for (int qt = 0; qt < 2; qt++)
#pragma unroll
    for (int i = 0; i < 4; i++) {
      oacc[qt][i] = f32x4{0.f, 0.f, 0.f, 0.f};
      suml[qt][i] = 0.f;
    }

  int klim = ((len + 63) >> 6) << 6;  // block-uniform, <= 1024

  gl_lds16(K + (size_t)srow * 64 + skg, Ks[0][0] + t * 8);
  gl_lds16(K + (size_t)srow * 64 + 32 + skg, Ks[0][1] + t * 8);
  __syncthreads();

  for (int k0 = 0; k0 < klim; k0 += 64) {
    int cur = (k0 >> 6) & 1;
    if (k0 + 64 < klim) {
      int nx = cur ^ 1, kn = k0 + 64;
      gl_lds16(K + (size_t)(kn + srow) * 64 + skg, Ks[nx][0] + t * 8);
      gl_lds16(K + (size_t)(kn + srow) * 64 + 32 + skg, Ks[nx][1] + t * 8);
    }

    // T14: issue V loads for nt=0,1 now; consumed after QK (~600cy cover).
    bf16x8 vr[4][2];
#pragma unroll
    for (int nt = 0; nt < 2; nt++) {
      vr[nt][0] = *(const bf16x8*)(VT + (size_t)(nt * 16 + col) * 1024 + k0 +
                                   quad * 8);
      vr[nt][1] = *(const bf16x8*)(VT + (size_t)(nt * 16 + col) * 1024 + k0 +
                                   32 + quad * 8);
    }

#pragma unroll
    for (int qt = 0; qt < 2; qt++) {
      f32x4 s[4];
#pragma unroll
      for (int ks = 0; ks < 4; ks++) s[ks] = f32x4{0.f, 0.f, 0.f, 0.f};
      __builtin_amdgcn_s_setprio(1);
#pragma unroll
      for (int ks = 0; ks < 4; ks++) {
        bf16x8 klo =
            *(const bf16x8*)(Ks[cur][0] + (ks * 16 + col) * 32 + rslot);
        bf16x8 khi =
            *(const bf16x8*)(Ks[cur][1] + (ks * 16 + col) * 32 + rslot);
        s[ks] = __builtin_amdgcn_mfma_f32_16x16x32_bf16(qf[qt][0], klo, s[ks],
                                                        0, 0, 0);
        s[ks] = __builtin_amdgcn_mfma_f32_16x16x32_bf16(qf[qt][1], khi, s[ks],
                                                        0, 0, 0);
      }
      __builtin_amdgcn_s_setprio(0);
#pragma unroll
      for (int ks = 0; ks < 4; ks++) {
#pragma unroll
        for (int r = 0; r < 4; r++) {
          float e = (k0 + ks * 16 + col < len) ? __expf(s[ks][r]) : 0.f;
          suml[qt][r] += e;
          myP[(qt * 16 + quad * 4 + r) * 72 + ks * 16 + col] = f2b(e);
        }
      }
    }

    // T14: issue V loads for nt=2,3; consumed after the P round-trip.
#pragma unroll
    for (int nt = 2; nt < 4; nt++) {
      vr[nt][0] = *(const bf16x8*)(VT + (size_t)(nt * 16 + col) * 1024 + k0 +
                                   quad * 8);
      vr[nt][1] = *(const bf16x8*)(VT + (size_t)(nt * 16 + col) * 1024 + k0 +
                                   32 + quad * 8);
    }

#pragma unroll
    for (int qt = 0; qt < 2; qt++) {
      bf16x8 pf0 = *(const bf16x8*)(myP + (qt * 16 + col) * 72 + quad * 8);
      bf16x8 pf1 = *(const bf16x8*)(myP + (qt * 16 + col) * 72 + 32 + quad * 8);
      __builtin_amdgcn_s_setprio(1);
#pragma unroll
      for (int nt = 0; nt < 4; nt++) {
        oacc[qt][nt] = __builtin_amdgcn_mfma_f32_16x16x32_bf16(
            pf0, vr[nt][0], oacc[qt][nt], 0, 0, 0);
        oacc[qt][nt] = __builtin_amdgcn_mfma_f32_16x16x32_bf16(
            pf1, vr[nt][1], oacc[qt][nt], 0, 0, 0);
      }
      __builtin_amdgcn_s_setprio(0);
    }
    __syncthreads();
  }
#pragma unroll
  for (int qt = 0; qt < 2; qt++)
#pragma unroll
    for (int r = 0; r < 4; r++) {
      suml[qt][r] += __shfl_xor(suml[qt][r], 1);
      suml[qt][r] += __shfl_xor(suml[qt][r], 2);
      suml[qt][r] += __shfl_xor(suml[qt][r], 4);
      suml[qt][r] += __shfl_xor(suml[qt][r], 8);
    }
#pragma unroll
  for (int qt = 0; qt < 2; qt++)
#pragma unroll
    for (int nt = 0; nt < 4; nt++)
#pragma unroll
      for (int r = 0; r < 4; r++) {
        int q = qb0 + qt * 64 + quad * 4 + r;
        float v = (q < len) ? oacc[qt][nt][r] / suml[qt][r] : 0.f;
        Ob[((size_t)bl * 1024 + q) * 1024 + h * 64 + nt * 16 + col] = f2b(v);
      }
}

// GEMM2. Grid (8, nb*8). Output dtype follows flag.
// R19 skip: fully-masked blocks write the bias broadcast (0 @ w_o + b_o).
__global__ __launch_bounds__(256, 3) void gemm_out_k(
    const short* __restrict__ O, const short* __restrict__ wT,
    const char* __restrict__ bias, char* __restrict__ out,
    const int* __restrict__ flag, int m_base,
    const int* __restrict__ lengths) {
  __shared__ __align__(16) short Ls[3 * 8192];
  int isf32 = *flag;
  int m0 = blockIdx.y * 128, n0 = blockIdx.x * 128;
  int gm = m_base + m0;
  int len = lengths[gm >> 10];
  int mloc = gm & 1023;
  if (mloc >= len) {
    int t = threadIdx.x;
    int nn = n0 + (t & 127);
    float bv = ldbias(bias, nn, isf32);
    int mstart = m0 + (t >> 7) * 64;
    for (int j = 0; j < 64; j++) {
      size_t idx = (size_t)(m_base + mstart + j) * 1024 + nn;
      if (isf32)
        ((float*)out)[idx] = bv;
      else
        ((short*)out)[idx] = f2b(bv);
    }
    return;
  }
  f32x4 acc[4][4];
#pragma unroll
  for (int i = 0; i < 4; i++)
#pragma unroll
    for (int j = 0; j < 4; j++) acc[i][j] = f32x4{0.f, 0.f, 0.f, 0.f};
  gemm_core(O, wT, Ls, m0, n0, acc);
  int t = threadIdx.x, wave = t >> 6, lane = t & 63, quad = lane >> 4,
      col = lane & 15;
  int wm = (wave >> 1) * 64, wn = (wave & 1) * 64;
#pragma unroll
  for (int j = 0; j < 4; j++) {
    int n = n0 + wn + j * 16 + col;
    float bv = ldbias(bias, n, isf32);
#pragma unroll
    for (int i = 0; i < 4; i++) {
#pragma unroll
      for (int r = 0; r < 4; r++) {
        int m = m0 + wm + i * 16 + quad * 4 + r;
        size_t idx = (size_t)(m_base + m) * 1024 + n;
        float val = acc[i][j][r] + bv;
        if (isf32)
          ((float*)out)[idx] = val;
        else
          ((short*)out)[idx] = f2b(val);
      }
    }
  }
}

extern "C" void kernel_launch(void* const* d_in, const int* in_sizes, int n_in,
                              void* d_out, int out_size, void* d_ws,
                              size_t ws_size, hipStream_t stream) {
  const char* x = (const char*)d_in[0];
  const int* lengths = (const int*)d_in[1];
  const char* w_qkv = (const char*)d_in[2];
  const char* b_qkv = (const char*)d_in[3];
  const char* w_o = (const char*)d_in[4];
  const char* b_o = (const char*)d_in[5];
  char* out = (char*)d_out;

  char* ws = (char*)d_ws;
  int* flag = (int*)ws;        ws += 256;
  short* wT_qkv = (short*)ws;  ws += (size_t)3072 * 1024 * 2;  // 6.3 MB
  short* wT_o = (short*)ws;    ws += (size_t)1024 * 1024 * 2;  // 2.1 MB
  char* dynbase = ws;
  size_t fixed = (size_t)(dynbase - (char*)d_ws);
  size_t per_batch = (size_t)16 * 1024 * 64 * 2;  // 2.10 MB / tensor
  size_t need_full = fixed + 4 * 8 * per_batch;   // ~75.8 MB (fits, R3-R5)
  int nb = (ws_size >= need_full) ? 8 : 1;

  // xbf aliases Ob: x consumed by GEMM1 before attn writes Ob.
  short* xbf_Ob = (short*)dynbase;
  short* Qb = xbf_Ob + (size_t)nb * 16 * 1024 * 64;
  short* Kb = Qb + (size_t)nb * 16 * 1024 * 64;
  short* VTb = Kb + (size_t)nb * 16 * 1024 * 64;

  dim3 blk(256);
  probe_k<<<1, 64, 0, stream>>>((const short*)x, flag);
  transpose_k<<<dim3(48, 16), blk, 0, stream>>>(w_qkv, wT_qkv, 1024, 3072, flag);
  transpose_k<<<dim3(16, 16), blk, 0, stream>>>(w_o, wT_o, 1024, 1024, flag);
  for (int b0 = 0; b0 < 8; b0 += nb) {
    cvt_x_k<<<dim3(nb * 512), blk, 0, stream>>>(x, xbf_Ob, flag, b0);
    gemm_qkv_k<<<dim3(24, nb * 8), blk, 0, stream>>>(xbf_Ob, wT_qkv, b_qkv, Qb,
                                                     Kb, VTb, flag, lengths,
                                                     b0);
    attn_k<<<dim3(8, nb * 16), blk, 0, stream>>>(Qb, Kb, VTb, lengths, xbf_Ob,
                                                 b0);
    gemm_out_k<<<dim3(8, nb * 8), blk, 0, stream>>>(xbf_Ob, wT_o, b_o, out,
                                                    flag, b0 * 1024, lengths);
  }
}